// Round 3
// baseline (1260.781 us; speedup 1.0000x reference)
//
#include <hip/hip_runtime.h>
#include <hip/hip_fp8.h>
#include <cstdint>
#include <cstddef>

// Problem dims (TemporalLSTM_77455440216810)
#define IDIM 128   // INPUT_DIM
#define HS   256   // HIDDEN
#define SEQL 512   // SEQ
#define TOUT 24    // OUT (scan steps)
#define TMP  64    // TEMP
#define NB   512   // B
#define G4   1024  // 4*HS

typedef unsigned short u16;
typedef unsigned int   u32;
typedef __attribute__((ext_vector_type(8))) short bf16x8;  // 8 bf16 (MFMA A/B frag)
typedef __attribute__((ext_vector_type(4))) float f32x4;   // MFMA C/D frag

// ================= LDS layout, main kernel (bytes), total 148240 =================
#define OFF_HFRAG 0        // 2 x (512x128 fp8) MFMA-A frags: 131072
#define OFF_GATES 131072   // f32 [2][1024] gates (MFMA output): 8192
#define OFF_E     139264   // f32 [2][512]: 4096
#define OFF_CUABA 143360   // f32 [2][64] c@Ua+ba: 512
#define OFF_XBF   143872   // u16 [2][384] = [ctx(128)|h(256)] bf16 A-rows: 1536
#define OFF_CF8   145408   // u8  [2][256] c in fp8 (attention A-rows): 512
#define OFF_CL    145920   // f32 [2][256] c state: 2048
#define OFF_RED   147968   // f32 [2][24] reductions: 256
#define OFF_Y     148224   // f32 y[2] + pad: 16
#define SMEM_BYTES 148240

// ---- fallback (round-2 kernel, fp32 weights) LDS ----
#define FB_OFF_HFRAG 0
#define FB_OFF_GATEP 131072
#define FB_OFF_E     147456
#define FB_OFF_CUAP  151552
#define FB_OFF_CTXP  153600
#define FB_OFF_H     155648
#define FB_OFF_C     157696
#define FB_OFF_CTX   159744
#define FB_OFF_CUABA 160768
#define FB_OFF_VA    161280
#define FB_OFF_RED   161536
#define FB_OFF_Y     161728
#define FB_OFF_INVD  161736
#define FB_SMEM_BYTES 161744

__device__ __forceinline__ u16 f2bf(float f) {
  union { float f; u32 u; } v; v.f = f;
  u32 r = v.u + 0x7FFFu + ((v.u >> 16) & 1u);
  return (u16)(r >> 16);
}
__device__ __forceinline__ float bf2f(u16 s) {
  union { u32 u; float f; } v; v.u = ((u32)s) << 16; return v.f;
}
__device__ __forceinline__ float bflo(u32 u) {
  union { u32 u; float f; } v; v.u = u << 16; return v.f;
}
__device__ __forceinline__ float bfhi(u32 u) {
  union { u32 u; float f; } v; v.u = u & 0xFFFF0000u; return v.f;
}
__device__ __forceinline__ u32 pkbf(float a, float b) {
  return (u32)f2bf(a) | ((u32)f2bf(b) << 16);
}
// fp8 e4m3 (OCP)
__device__ __forceinline__ u32 pk4_fp8(float a, float b, float c, float d) {
#if __has_builtin(__builtin_amdgcn_cvt_pk_fp8_f32)
  u32 v = (u32)__builtin_amdgcn_cvt_pk_fp8_f32(a, b, 0, false);
  v = (u32)__builtin_amdgcn_cvt_pk_fp8_f32(c, d, (int)v, true);
  return v;
#else
  __hip_fp8_e4m3 x(a), y(b), z(c), w(d);
  return (u32)x.__x | ((u32)y.__x << 8) | ((u32)z.__x << 16) | ((u32)w.__x << 24);
#endif
}
__device__ __forceinline__ unsigned char f2fp8(float a) {
  __hip_fp8_e4m3 x(a);
  return x.__x;
}
template <int S>
__device__ __forceinline__ float fp8_f32(u32 v) {
#if __has_builtin(__builtin_amdgcn_cvt_f32_fp8)
  return __builtin_amdgcn_cvt_f32_fp8((int)v, S);
#else
  __hip_fp8_e4m3 x; x.__x = (unsigned char)(v >> (8 * S)); return (float)x;
#endif
}
// Pade(3/2) tanh for attention scores (error attenuated by Va-dot + /16 + softmax)
__device__ __forceinline__ float tanh_fast(float x) {
  float x2 = x * x;
  float r = x * (27.0f + x2) * __builtin_amdgcn_rcpf(27.0f + 9.0f * x2);
  return fminf(fmaxf(r, -1.0f), 1.0f);
}
__device__ __forceinline__ float sigmoid_acc(float x) {
  return __builtin_amdgcn_rcpf(1.0f + __builtin_exp2f(-1.4426950408889634f * x));
}
__device__ __forceinline__ float tanh_acc(float x) {
  return 1.0f - 2.0f * __builtin_amdgcn_rcpf(1.0f + __builtin_exp2f(2.8853900817779268f * x));
}

// ====================== prep kernels: swizzle weights into MFMA frag layouts =====
// WU B-frags bf16: per t, frag f = nt*12+kc (nt 0..63 over N=1024, kc 0..11 over
// K=384=[W rows 0..127 | U rows 0..255]); lane: n = nt*16+(lane&15),
// k = kc*32+(lane>>4)*8+j. 16 B/lane/frag.
__global__ void prep_wu_kernel(const float* __restrict__ W, const float* __restrict__ U,
                               u16* __restrict__ dst) {
  int gid = blockIdx.x * 256 + threadIdx.x;  // < 24*768*64
  int lane = gid & 63;
  int tf = gid >> 6;          // t*768 + f
  int fi = tf % 768;
  int t = tf / 768;
  int nt = fi / 12, kc = fi - nt * 12;
  int n = nt * 16 + (lane & 15);
  int k0 = kc * 32 + (lane >> 4) * 8;
  u32 dw[4];
#pragma unroll
  for (int p = 0; p < 4; ++p) {
    int ka = k0 + p * 2, kb = ka + 1;
    float f0 = (ka < 128) ? W[((size_t)ka * TOUT + t) * G4 + n]
                          : U[((size_t)(ka - 128) * TOUT + t) * G4 + n];
    float f1 = (kb < 128) ? W[((size_t)kb * TOUT + t) * G4 + n]
                          : U[((size_t)(kb - 128) * TOUT + t) * G4 + n];
    dw[p] = pkbf(f0, f1);
  }
  *(uint4*)(dst + (size_t)gid * 8) = make_uint4(dw[0], dw[1], dw[2], dw[3]);
}

#define N_WA (TOUT * 16 * 64)
#define N_UA (TOUT * 32 * 64)
#define N_VAT (TOUT * TMP)
#define N_WY (TOUT * G4)
// Wa fp8 B-frags (f = nt*4+kc, N=64 over j, K=128 over d); Ua fp8 B-frags
// (f = nt*8+kc, N=64 over j, K=256 over d); Vat[t][j] transpose; Wy bf16.
__global__ void prep_misc_kernel(const float* __restrict__ Wa, const float* __restrict__ Ua,
                                 const float* __restrict__ Va, const float* __restrict__ Wy,
                                 unsigned char* __restrict__ WaD, unsigned char* __restrict__ UaD,
                                 float* __restrict__ VatD, u16* __restrict__ WyD) {
  int gid = blockIdx.x * 256 + threadIdx.x;
  if (gid < N_WA) {
    int lane = gid & 63, fi = (gid >> 6) & 15, t = gid >> 10;
    int nt = fi >> 2, kc = fi & 3;
    int n = nt * 16 + (lane & 15);
    int k0 = kc * 32 + (lane >> 4) * 8;
    float f[8];
#pragma unroll
    for (int j = 0; j < 8; ++j) f[j] = Wa[((size_t)(k0 + j) * TOUT + t) * TMP + n];
    *(uint2*)(WaD + (size_t)gid * 8) =
        make_uint2(pk4_fp8(f[0], f[1], f[2], f[3]), pk4_fp8(f[4], f[5], f[6], f[7]));
  } else if (gid < N_WA + N_UA) {
    int g = gid - N_WA;
    int lane = g & 63, fi = (g >> 6) & 31, t = g >> 11;
    int nt = fi >> 3, kc = fi & 7;
    int n = nt * 16 + (lane & 15);
    int k0 = kc * 32 + (lane >> 4) * 8;
    float f[8];
#pragma unroll
    for (int j = 0; j < 8; ++j) f[j] = Ua[((size_t)(k0 + j) * TOUT + t) * TMP + n];
    *(uint2*)(UaD + (size_t)g * 8) =
        make_uint2(pk4_fp8(f[0], f[1], f[2], f[3]), pk4_fp8(f[4], f[5], f[6], f[7]));
  } else if (gid < N_WA + N_UA + N_VAT) {
    int g = gid - N_WA - N_UA;
    int t = g >> 6, j = g & 63;
    VatD[g] = Va[j * TOUT + t];
  } else if (gid < N_WA + N_UA + N_VAT + N_WY) {
    int g = gid - N_WA - N_UA - N_VAT;
    WyD[g] = f2bf(Wy[g]);
  }
}

// =============================== main persistent kernel ==========================
// One WG = 2 batch elements, 1024 threads, 24 steps. All heavy math on MFMA;
// weights pre-swizzled into fragment layout in ws (linear dwordx4 loads).
__global__ __launch_bounds__(1024, 4) void lstm_attn_mfma(
    const float* __restrict__ H, const float* __restrict__ y0, const float* __restrict__ emb,
    const float* __restrict__ ba, const float* __restrict__ bias, const float* __restrict__ fcw,
    const float* __restrict__ fcb, const u16* __restrict__ WUf,
    const unsigned char* __restrict__ Waf, const unsigned char* __restrict__ Uaf,
    const float* __restrict__ Vat, const u16* __restrict__ Wyb, float* __restrict__ out) {
  const int bg0 = blockIdx.x * 2;
  const int tid = threadIdx.x;
  const int lane = tid & 63;
  const int wv = tid >> 6;  // 0..15
  extern __shared__ char smem[];
  float* gatesL = (float*)(smem + OFF_GATES);
  float* eL     = (float*)(smem + OFF_E);
  float* cuabaL = (float*)(smem + OFF_CUABA);
  u16*   xbf    = (u16*)(smem + OFF_XBF);
  unsigned char* cf8 = (unsigned char*)(smem + OFF_CF8);
  float* cL     = (float*)(smem + OFF_CL);
  float* redL   = (float*)(smem + OFF_RED);
  float* yL     = (float*)(smem + OFF_Y);

  // ---- one-time: stage H (both b) into LDS as fp8 MFMA-A fragments ----
  // A-frag: m = lane&15, k = (lane>>4)*8+j. chunk (b,l,oct) at
  // b*65536 + ((mtile*4+kc)*64 + q*16 + lm)*8, mtile=l>>4, lm=l&15, kc=oct>>2, q=oct&3
#pragma unroll 2
  for (int it = 0; it < 16; ++it) {
    int ch = it * 1024 + tid;  // 0..16383
    int bl = ch >> 13;
    int c2 = ch & 8191;
    int l = c2 >> 4, oct = c2 & 15;
    const float* src = H + (size_t)(bg0 + bl) * (SEQL * IDIM) + l * IDIM + oct * 8;
    float4 a = *(const float4*)src;
    float4 c4 = *(const float4*)(src + 4);
    u32 lo = pk4_fp8(a.x, a.y, a.z, a.w);
    u32 hi = pk4_fp8(c4.x, c4.y, c4.z, c4.w);
    int mtile = l >> 4, lm = l & 15, kc = oct >> 2, q = oct & 3;
    *(uint2*)(smem + OFF_HFRAG + (size_t)bl * 65536 +
              (size_t)(((mtile * 4 + kc) * 64 + q * 16 + lm)) * 8) = make_uint2(lo, hi);
  }
  if (tid < 512) {  // carries: h -> xbf (bf16), c -> cL (f32) + cf8 (fp8)
    int b = tid >> 8, i = tid & 255;
    float h0 = emb[(size_t)(bg0 + b) * 512 + i];
    float c0 = emb[(size_t)(bg0 + b) * 512 + 256 + i];
    xbf[b * 384 + 128 + i] = f2bf(h0);
    cL[b * 256 + i] = c0;
    cf8[b * 256 + i] = f2fp8(c0);
  }
  if (tid < 2) yL[tid] = y0[bg0 + tid];
  __syncthreads();

#pragma unroll 1
  for (int t = 0; t < TOUT; ++t) {
    // ===== A: load Wa B-frags (all waves, registers) + c@Ua via fp8 MFMA (waves 0-3)
    long wafr[16];
    {
      const char* wab = (const char*)Waf + (size_t)t * (16 * 64 * 8);
#pragma unroll
      for (int f = 0; f < 16; ++f) wafr[f] = *(const long*)(wab + ((size_t)(f * 64 + lane)) * 8);
    }
    if (wv < 4) {  // c@Ua: M=2(pad16) x N=64 x K=256; wave wv owns n-tile wv
      int m = lane & 15, q = lane >> 4;
      const char* uab = (const char*)Uaf + (size_t)t * (32 * 64 * 8);
      f32x4 acc = 0;
#pragma unroll
      for (int kc = 0; kc < 8; ++kc) {
        long bf = *(const long*)(uab + ((size_t)((wv * 8 + kc) * 64 + lane)) * 8);
        long af = 0;
        if (m < 2) af = *(const long*)(smem + OFF_CF8 + m * 256 + kc * 32 + q * 8);
        acc = __builtin_amdgcn_mfma_f32_16x16x32_fp8_fp8(af, bf, acc, 0, 0, 0);
      }
      if (lane < 16) {  // D rows 0/1 = b0/b1 live in lanes 0-15, regs 0/1
        int j = wv * 16 + lane;
        float bav = ba[t * TMP + j];
        cuabaL[j] = acc[0] + bav;
        cuabaL[64 + j] = acc[1] + bav;
      }
    }
    __syncthreads();  // S1: cuabaL ready

    // ===== P1: e-pass  T = H_b @ Wa_t (fp8 MFMA) -> tanh -> Va dot =====
    {
      const int b = wv >> 3, m8 = wv & 7;
      const int lm = lane & 15, q = lane >> 4;
      float cb[4], vv[4];
#pragma unroll
      for (int nt = 0; nt < 4; ++nt) {
        cb[nt] = cuabaL[b * 64 + nt * 16 + lm];
        vv[nt] = Vat[t * TMP + nt * 16 + lm];
      }
#pragma unroll
      for (int mm = 0; mm < 4; ++mm) {
        int mtile = m8 * 4 + mm;
        f32x4 acc0 = 0, acc1 = 0, acc2 = 0, acc3 = 0;
#pragma unroll
        for (int kc = 0; kc < 4; ++kc) {
          long af = *(const long*)(smem + OFF_HFRAG + (size_t)b * 65536 +
                                   (size_t)(((mtile * 4 + kc) * 64 + lane)) * 8);
          acc0 = __builtin_amdgcn_mfma_f32_16x16x32_fp8_fp8(af, wafr[0 * 4 + kc], acc0, 0, 0, 0);
          acc1 = __builtin_amdgcn_mfma_f32_16x16x32_fp8_fp8(af, wafr[1 * 4 + kc], acc1, 0, 0, 0);
          acc2 = __builtin_amdgcn_mfma_f32_16x16x32_fp8_fp8(af, wafr[2 * 4 + kc], acc2, 0, 0, 0);
          acc3 = __builtin_amdgcn_mfma_f32_16x16x32_fp8_fp8(af, wafr[3 * 4 + kc], acc3, 0, 0, 0);
        }
        // C/D: col = nt*16+(lane&15), row = mtile*16 + (lane>>4)*4 + r
#pragma unroll
        for (int r = 0; r < 4; ++r) {
          float v = tanh_fast(acc0[r] + cb[0]) * vv[0] + tanh_fast(acc1[r] + cb[1]) * vv[1] +
                    tanh_fast(acc2[r] + cb[2]) * vv[2] + tanh_fast(acc3[r] + cb[3]) * vv[3];
          v += __shfl_xor(v, 1);
          v += __shfl_xor(v, 2);
          v += __shfl_xor(v, 4);
          v += __shfl_xor(v, 8);
          if (lm == 0) eL[b * 512 + mtile * 16 + q * 4 + r] = v;
        }
      }
    }
    __syncthreads();  // S2: eL ready

    // ===== P2: per-b softmax (logits = e/16); fold y-finalize of step t-1 =====
    float invden;
    {
      int b = tid >> 9;
      int w8 = (tid >> 6) & 7;
      float v = eL[tid];
      float m = v;
#pragma unroll
      for (int msk = 1; msk <= 32; msk <<= 1) m = fmaxf(m, __shfl_xor(m, msk));
      if (lane == 0) redL[b * 24 + w8] = m;
      if (t > 0 && (tid == 0 || tid == 512)) {  // y_{t-1} finalize (redL[16..19] from prev P5)
        int b2 = tid >> 9;
        float y = redL[b2 * 24 + 16] + redL[b2 * 24 + 17] + redL[b2 * 24 + 18] +
                  redL[b2 * 24 + 19] + fcb[t - 1];
        yL[b2] = y;
        out[(size_t)(bg0 + b2) * TOUT + (t - 1)] = y;
      }
      __syncthreads();
      float M = redL[b * 24];
#pragma unroll
      for (int p = 1; p < 8; ++p) M = fmaxf(M, redL[b * 24 + p]);
      float pv = __builtin_exp2f((v - M) * 0.0901684400347379f);  // (1/16)*log2(e)
      eL[tid] = pv;
      float s = pv;
#pragma unroll
      for (int msk = 1; msk <= 32; msk <<= 1) s += __shfl_xor(s, msk);
      if (lane == 0) redL[b * 24 + 8 + w8] = s;
      __syncthreads();  // also makes all eL exp-values visible for P3
      float den = 0.f;
#pragma unroll
      for (int p = 0; p < 8; ++p) den += redL[b * 24 + 8 + p];
      invden = __builtin_amdgcn_rcpf(den);
    }

    // ===== P3: ctx_d = invden * sum_l p_l H[l][d]; write ctx -> xbf (bf16) =====
    {
      int b = tid >> 9, s = tid & 511;
      int lsub = s & 15, dq = s >> 4;            // dq: d-chunk of 4 (0..31)
      int kc = dq >> 3, q = (dq >> 1) & 3, sel = dq & 1;
      const char* hb = smem + OFF_HFRAG + (size_t)b * 65536;
      float a0 = 0.f, a1 = 0.f, a2 = 0.f, a3 = 0.f;
#pragma unroll 8
      for (int mt = 0; mt < 32; ++mt) {
        u32 hv = *(const u32*)(hb + (size_t)(((mt * 4 + kc) * 64 + q * 16 + lsub)) * 8 + sel * 4);
        float p = eL[b * 512 + mt * 16 + lsub];
        a0 += p * fp8_f32<0>(hv);
        a1 += p * fp8_f32<1>(hv);
        a2 += p * fp8_f32<2>(hv);
        a3 += p * fp8_f32<3>(hv);
      }
#pragma unroll
      for (int msk = 1; msk <= 8; msk <<= 1) {
        a0 += __shfl_xor(a0, msk); a1 += __shfl_xor(a1, msk);
        a2 += __shfl_xor(a2, msk); a3 += __shfl_xor(a3, msk);
      }
      if (lsub == 0) {
        u32* dst = (u32*)(xbf + b * 384 + dq * 4);
        dst[0] = pkbf(a0 * invden, a1 * invden);
        dst[1] = pkbf(a2 * invden, a3 * invden);
      }
    }
    __syncthreads();  // S4: xbf complete (ctx this step, h from prev step)

    // ===== P4: gates = [ctx|h] @ [W;U] via bf16 MFMA (M=2 pad16, N=1024, K=384) =====
    {
      int m = lane & 15, q = lane >> 4;
      bf16x8 afr[12];
#pragma unroll
      for (int kc = 0; kc < 12; ++kc) {
        bf16x8 z = {};
        if (m < 2) z = *(const bf16x8*)(xbf + m * 384 + kc * 32 + q * 8);
        afr[kc] = z;
      }
      const u16* wub = WUf + (size_t)t * (768 * 64 * 8);
#pragma unroll
      for (int ntl = 0; ntl < 4; ++ntl) {
        int nt = wv * 4 + ntl;
        f32x4 acc = 0;
#pragma unroll
        for (int kc = 0; kc < 12; ++kc) {
          bf16x8 bfr = *(const bf16x8*)(wub + (size_t)((nt * 12 + kc) * 64 + lane) * 8);
          acc = __builtin_amdgcn_mfma_f32_16x16x32_bf16(afr[kc], bfr, acc, 0, 0, 0);
        }
        if (lane < 16) {
          gatesL[nt * 16 + lane] = acc[0];         // b0
          gatesL[1024 + nt * 16 + lane] = acc[1];  // b1
        }
      }
    }
    __syncthreads();  // S5: gatesL ready

    // ===== P5: LSTM cell + outputs =====
    float ypart = 0.f;
    int bh = tid >> 8, hc = tid & 255;
    if (tid < 512) {
      float yprev = yL[bh];
      float gv[4];
#pragma unroll
      for (int gi = 0; gi < 4; ++gi) {
        int col = gi * 256 + hc;
        float s = gatesL[bh * 1024 + col] + bias[(size_t)t * G4 + col] +
                  yprev * bf2f(Wyb[t * G4 + col]);
        gv[gi] = s;
      }
      float ig = sigmoid_acc(gv[0]);
      float fg = sigmoid_acc(gv[1]);
      float gg = tanh_acc(gv[2]);
      float og = sigmoid_acc(gv[3]);
      float cn = fg * cL[bh * 256 + hc] + ig * gg;
      float hn = og * tanh_acc(cn);
      cL[bh * 256 + hc] = cn;
      cf8[bh * 256 + hc] = f2fp8(cn);
      xbf[bh * 384 + 128 + hc] = f2bf(hn);
      out[12288 + ((size_t)(bg0 + bh) * TOUT + t) * HS + hc] = hn;
      ypart = hn * fcw[t * HS + hc];
    }
#pragma unroll
    for (int msk = 1; msk <= 32; msk <<= 1) ypart += __shfl_xor(ypart, msk);
    if (tid < 512 && lane == 0) redL[bh * 24 + 16 + ((tid >> 6) & 3)] = ypart;
    __syncthreads();  // S6: end of step
  }
  // final y (t = TOUT-1)
  if (tid == 0 || tid == 512) {
    int b2 = tid >> 9;
    float y = redL[b2 * 24 + 16] + redL[b2 * 24 + 17] + redL[b2 * 24 + 18] +
              redL[b2 * 24 + 19] + fcb[TOUT - 1];
    out[(size_t)(bg0 + b2) * TOUT + (TOUT - 1)] = y;
  }
}

// ====================== fallback (round-2 kernel, fp32 weights) ==================
__global__ __launch_bounds__(1024, 4) void lstm_attn_fb(
    const float* __restrict__ H, const float* __restrict__ y0, const float* __restrict__ emb,
    const float* __restrict__ Wa, const float* __restrict__ UaF, const float* __restrict__ ba,
    const float* __restrict__ Va, const float* __restrict__ WF, const float* __restrict__ UF,
    const float* __restrict__ bias, const float* __restrict__ WyF, const float* __restrict__ fcw,
    const float* __restrict__ fcb, float* __restrict__ out) {
  const int bg0 = blockIdx.x * 2;
  const int tid = threadIdx.x;
  const int lane = tid & 63;
  const int wv = tid >> 6;
  extern __shared__ char smem[];
  float* eL     = (float*)(smem + FB_OFF_E);
  float* hL     = (float*)(smem + FB_OFF_H);
  float* cL     = (float*)(smem + FB_OFF_C);
  float* ctxL   = (float*)(smem + FB_OFF_CTX);
  float* cuapL  = (float*)(smem + FB_OFF_CUAP);
  float* ctxpL  = (float*)(smem + FB_OFF_CTXP);
  float* cuabaL = (float*)(smem + FB_OFF_CUABA);
  float* vaL    = (float*)(smem + FB_OFF_VA);
  float* redL   = (float*)(smem + FB_OFF_RED);
  float* yL     = (float*)(smem + FB_OFF_Y);
  float* invdL  = (float*)(smem + FB_OFF_INVD);
  u32* gatepU   = (u32*)(smem + FB_OFF_GATEP);

#pragma unroll 2
  for (int it = 0; it < 16; ++it) {
    int ch = it * 1024 + tid;
    int bl = ch >> 13;
    int c2 = ch & 8191;
    int l = c2 >> 4, oct = c2 & 15;
    const float* src = H + (size_t)(bg0 + bl) * (SEQL * IDIM) + l * IDIM + oct * 8;
    float4 a = *(const float4*)src;
    float4 c4 = *(const float4*)(src + 4);
    u32 lo = pk4_fp8(a.x, a.y, a.z, a.w);
    u32 hi = pk4_fp8(c4.x, c4.y, c4.z, c4.w);
    int mtile = l >> 4, lm = l & 15, kc = oct >> 2, q = oct & 3;
    *(uint2*)(smem + FB_OFF_HFRAG + (size_t)bl * 65536 +
              (size_t)(((mtile * 4 + kc) * 64 + q * 16 + lm)) * 8) = make_uint2(lo, hi);
  }
  if (tid < 512) {
    int b = tid >> 8, i = tid & 255;
    hL[b * 256 + i] = emb[(size_t)(bg0 + b) * 512 + i];
    cL[b * 256 + i] = emb[(size_t)(bg0 + b) * 512 + 256 + i];
  }
  if (tid < 2) yL[tid] = y0[bg0 + tid];
  __syncthreads();

#pragma unroll 1
  for (int t = 0; t < TOUT; ++t) {
    {
      int nt = tid >> 8, kc = (tid >> 6) & 3, l6 = tid & 63;
      int lm = l6 & 15, q = l6 >> 4;
      int n = nt * 16 + lm;
      float f[8];
#pragma unroll
      for (int j = 0; j < 8; ++j) {
        int k = kc * 32 + q * 8 + j;
        f[j] = Wa[((size_t)k * TOUT + t) * TMP + n];
      }
      *(uint2*)(smem + FB_OFF_GATEP + (size_t)tid * 8) =
          make_uint2(pk4_fp8(f[0], f[1], f[2], f[3]), pk4_fp8(f[4], f[5], f[6], f[7]));
    }
    if (tid < 128) {
      int j2 = tid & 31, part = tid >> 5;
      float s00 = 0.f, s01 = 0.f, s10 = 0.f, s11 = 0.f;
#pragma unroll 8
      for (int i = 0; i < 64; ++i) {
        int d = part * 64 + i;
        const float* up = UaF + ((size_t)d * TOUT + t) * TMP + j2 * 2;
        float u0 = up[0], u1 = up[1];
        float c0 = cL[d], c1 = cL[256 + d];
        s00 += c0 * u0; s01 += c0 * u1;
        s10 += c1 * u0; s11 += c1 * u1;
      }
      cuapL[(0 * 4 + part) * 64 + j2 * 2] = s00;
      cuapL[(0 * 4 + part) * 64 + j2 * 2 + 1] = s01;
      cuapL[(1 * 4 + part) * 64 + j2 * 2] = s10;
      cuapL[(1 * 4 + part) * 64 + j2 * 2 + 1] = s11;
    }
    __syncthreads();
    if (tid < 128) {
      int b = tid >> 6, j = tid & 63;
      float s = 0.f;
#pragma unroll
      for (int p = 0; p < 4; ++p) s += cuapL[(b * 4 + p) * 64 + j];
      cuabaL[b * 64 + j] = s + ba[t * TMP + j];
      if (tid < 64) vaL[j] = Va[j * TOUT + t];
    }
    __syncthreads();
    {
      const int b = wv >> 3, m8 = wv & 7;
      const int lm = lane & 15, q = lane >> 4;
      float cb[4], vv[4];
#pragma unroll
      for (int nt = 0; nt < 4; ++nt) {
        cb[nt] = cuabaL[b * 64 + nt * 16 + lm];
        vv[nt] = vaL[nt * 16 + lm];
      }
      long bfr[4][4];
#pragma unroll
      for (int nt = 0; nt < 4; ++nt)
#pragma unroll
        for (int kc = 0; kc < 4; ++kc)
          bfr[nt][kc] =
              *(const long*)(smem + FB_OFF_GATEP + (size_t)(((nt * 4 + kc) * 64 + lane)) * 8);
#pragma unroll
      for (int mm = 0; mm < 4; ++mm) {
        int mtile = m8 * 4 + mm;
        f32x4 acc0 = 0, acc1 = 0, acc2 = 0, acc3 = 0;
#pragma unroll
        for (int kc = 0; kc < 4; ++kc) {
          long af = *(const long*)(smem + FB_OFF_HFRAG + (size_t)b * 65536 +
                                   (size_t)(((mtile * 4 + kc) * 64 + lane)) * 8);
          acc0 = __builtin_amdgcn_mfma_f32_16x16x32_fp8_fp8(af, bfr[0][kc], acc0, 0, 0, 0);
          acc1 = __builtin_amdgcn_mfma_f32_16x16x32_fp8_fp8(af, bfr[1][kc], acc1, 0, 0, 0);
          acc2 = __builtin_amdgcn_mfma_f32_16x16x32_fp8_fp8(af, bfr[2][kc], acc2, 0, 0, 0);
          acc3 = __builtin_amdgcn_mfma_f32_16x16x32_fp8_fp8(af, bfr[3][kc], acc3, 0, 0, 0);
        }
#pragma unroll
        for (int r = 0; r < 4; ++r) {
          float v = tanh_fast(acc0[r] + cb[0]) * vv[0] + tanh_fast(acc1[r] + cb[1]) * vv[1] +
                    tanh_fast(acc2[r] + cb[2]) * vv[2] + tanh_fast(acc3[r] + cb[3]) * vv[3];
          v += __shfl_xor(v, 1);
          v += __shfl_xor(v, 2);
          v += __shfl_xor(v, 4);
          v += __shfl_xor(v, 8);
          if (lm == 0) eL[b * 512 + mtile * 16 + q * 4 + r] = v;
        }
      }
    }
    __syncthreads();
    {
      int b = tid >> 9;
      int w8 = (tid >> 6) & 7;
      float v = eL[tid];
      float m = v;
#pragma unroll
      for (int msk = 1; msk <= 32; msk <<= 1) m = fmaxf(m, __shfl_xor(m, msk));
      if (lane == 0) redL[b * 24 + w8] = m;
      __syncthreads();
      float M = redL[b * 24];
#pragma unroll
      for (int p = 1; p < 8; ++p) M = fmaxf(M, redL[b * 24 + p]);
      float pv = __builtin_exp2f((v - M) * 0.0901684400347379f);
      eL[tid] = pv;
      float s = pv;
#pragma unroll
      for (int msk = 1; msk <= 32; msk <<= 1) s += __shfl_xor(s, msk);
      if (lane == 0) redL[b * 24 + 8 + w8] = s;
      __syncthreads();
      float den = 0.f;
#pragma unroll
      for (int p = 0; p < 8; ++p) den += redL[b * 24 + 8 + p];
      if ((tid & 511) == 0) invdL[b] = __builtin_amdgcn_rcpf(den);
    }
    {
      int b = tid >> 9, stid = tid & 511;
      int lsub = stid & 15, dch = (stid >> 4) & 15, half = stid >> 8;
      int kc = dch >> 2, q = dch & 3;
      const char* hbase = smem + FB_OFF_HFRAG + (size_t)b * 65536;
      float a[8] = {0.f, 0.f, 0.f, 0.f, 0.f, 0.f, 0.f, 0.f};
#pragma unroll 4
      for (int i = 0; i < 16; ++i) {
        int mt = half * 16 + i;
        int l = mt * 16 + lsub;
        uint2 hv = *(const uint2*)(hbase + (size_t)(((mt * 4 + kc) * 64 + q * 16 + lsub)) * 8);
        float p = eL[b * 512 + l];
        a[0] += p * fp8_f32<0>(hv.x); a[1] += p * fp8_f32<1>(hv.x);
        a[2] += p * fp8_f32<2>(hv.x); a[3] += p * fp8_f32<3>(hv.x);
        a[4] += p * fp8_f32<0>(hv.y); a[5] += p * fp8_f32<1>(hv.y);
        a[6] += p * fp8_f32<2>(hv.y); a[7] += p * fp8_f32<3>(hv.y);
      }
#pragma unroll
      for (int msk = 1; msk <= 8; msk <<= 1)
#pragma unroll
        for (int j = 0; j < 8; ++j) a[j] += __shfl_xor(a[j], msk);
      if (lsub == 0) {
        float* dst = &ctxpL[b * 256 + half * 128 + dch * 8];
#pragma unroll
        for (int j = 0; j < 8; ++j) dst[j] = a[j];
      }
    }
    __syncthreads();
    if (tid < 256) {
      int b = tid >> 7, d = tid & 127;
      ctxL[b * 128 + d] = (ctxpL[b * 256 + d] + ctxpL[b * 256 + 128 + d]) * invdL[b];
    }
    __syncthreads();
    {
      int gc = tid & 255, dpart = tid >> 8;
      const int c0 = gc * 4;
      float g0[4] = {0.f, 0.f, 0.f, 0.f};
      float g1[4] = {0.f, 0.f, 0.f, 0.f};
      {
        const float* wpf = WF + ((size_t)(dpart * 32) * TOUT + t) * G4 + c0;
#pragma unroll 2
        for (int i4 = 0; i4 < 8; ++i4) {
          float4 cv0 = *(const float4*)&ctxL[dpart * 32 + i4 * 4];
          float4 cv1 = *(const float4*)&ctxL[128 + dpart * 32 + i4 * 4];
#pragma unroll
          for (int j4 = 0; j4 < 4; ++j4) {
            float4 wf = *(const float4*)wpf;
            wpf += (size_t)TOUT * G4;
            float cc0 = (j4 == 0) ? cv0.x : (j4 == 1) ? cv0.y : (j4 == 2) ? cv0.z : cv0.w;
            float cc1 = (j4 == 0) ? cv1.x : (j4 == 1) ? cv1.y : (j4 == 2) ? cv1.z : cv1.w;
            g0[0] += cc0 * wf.x; g0[1] += cc0 * wf.y; g0[2] += cc0 * wf.z; g0[3] += cc0 * wf.w;
            g1[0] += cc1 * wf.x; g1[1] += cc1 * wf.y; g1[2] += cc1 * wf.z; g1[3] += cc1 * wf.w;
          }
        }
      }
      {
        const float* upf = UF + ((size_t)(dpart * 64) * TOUT + t) * G4 + c0;
#pragma unroll 2
        for (int i4 = 0; i4 < 16; ++i4) {
          float4 hv0 = *(const float4*)&hL[dpart * 64 + i4 * 4];
          float4 hv1 = *(const float4*)&hL[256 + dpart * 64 + i4 * 4];
#pragma unroll
          for (int j4 = 0; j4 < 4; ++j4) {
            float4 wf = *(const float4*)upf;
            upf += (size_t)TOUT * G4;
            float hh0 = (j4 == 0) ? hv0.x : (j4 == 1) ? hv0.y : (j4 == 2) ? hv0.z : hv0.w;
            float hh1 = (j4 == 0) ? hv1.x : (j4 == 1) ? hv1.y : (j4 == 2) ? hv1.z : hv1.w;
            g0[0] += hh0 * wf.x; g0[1] += hh0 * wf.y; g0[2] += hh0 * wf.z; g0[3] += hh0 * wf.w;
            g1[0] += hh1 * wf.x; g1[1] += hh1 * wf.y; g1[2] += hh1 * wf.z; g1[3] += hh1 * wf.w;
          }
        }
      }
      *(uint2*)&gatepU[((0 * 4 + dpart) * 512) + gc * 2] =
          make_uint2(pkbf(g0[0], g0[1]), pkbf(g0[2], g0[3]));
      *(uint2*)&gatepU[((1 * 4 + dpart) * 512) + gc * 2] =
          make_uint2(pkbf(g1[0], g1[1]), pkbf(g1[2], g1[3]));
    }
    __syncthreads();
    float ypart = 0.f;
    int bh = tid >> 8, hc = tid & 255;
    if (tid < 512) {
      float yprev = yL[bh];
      float gv[4];
#pragma unroll
      for (int gi = 0; gi < 4; ++gi) {
        int col = gi * 256 + hc;
        int ci = col >> 1, sel = col & 1;
        float s = 0.f;
#pragma unroll
        for (int p = 0; p < 4; ++p) {
          u32 u = gatepU[(bh * 4 + p) * 512 + ci];
          s += sel ? bfhi(u) : bflo(u);
        }
        s += bias[(size_t)t * G4 + col];
        gv[gi] = s + yprev * WyF[t * G4 + col];
      }
      float ig = sigmoid_acc(gv[0]);
      float fg = sigmoid_acc(gv[1]);
      float gg = tanh_acc(gv[2]);
      float og = sigmoid_acc(gv[3]);
      float cn = fg * cL[bh * 256 + hc] + ig * gg;
      float hn = og * tanh_acc(cn);
      cL[bh * 256 + hc] = cn;
      hL[bh * 256 + hc] = hn;
      out[12288 + ((size_t)(bg0 + bh) * TOUT + t) * HS + hc] = hn;
      ypart = hn * fcw[t * HS + hc];
    }
#pragma unroll
    for (int msk = 1; msk <= 32; msk <<= 1) ypart += __shfl_xor(ypart, msk);
    if (tid < 512 && lane == 0) redL[bh * 24 + 16 + ((tid >> 6) & 3)] = ypart;
    __syncthreads();
    if (tid == 0 || tid == 512) {
      int b2 = tid >> 9;
      float y = redL[b2 * 24 + 16] + redL[b2 * 24 + 17] + redL[b2 * 24 + 18] +
                redL[b2 * 24 + 19] + fcb[t];
      yL[b2] = y;
      out[(size_t)(bg0 + b2) * TOUT + t] = y;
    }
    __syncthreads();
  }
}

extern "C" void kernel_launch(void* const* d_in, const int* in_sizes, int n_in, void* d_out,
                              int out_size, void* d_ws, size_t ws_size, hipStream_t stream) {
  const float* H    = (const float*)d_in[0];
  const float* y0   = (const float*)d_in[1];
  const float* emb  = (const float*)d_in[2];
  const float* Wa   = (const float*)d_in[3];
  const float* Ua   = (const float*)d_in[4];
  const float* ba   = (const float*)d_in[5];
  const float* Va   = (const float*)d_in[6];
  const float* W    = (const float*)d_in[7];
  const float* U    = (const float*)d_in[8];
  const float* bias = (const float*)d_in[9];
  const float* Wy   = (const float*)d_in[10];
  const float* fcw  = (const float*)d_in[11];
  const float* fcb  = (const float*)d_in[12];
  float* out = (float*)d_out;

  // ws layout (bytes)
  const size_t nWU = (size_t)TOUT * 768 * 64 * 8;  // u16 count = 9437184
  u16* WUf = (u16*)d_ws;
  unsigned char* Waf = (unsigned char*)(WUf + nWU);          // 196608 B
  unsigned char* Uaf = Waf + (size_t)N_WA * 8;               // 393216 B
  float* Vat = (float*)(Uaf + (size_t)N_UA * 8);             // 6144 B
  u16* Wyb = (u16*)(Vat + N_VAT);                            // 49152 B
  const size_t need = nWU * 2 + (size_t)N_WA * 8 + (size_t)N_UA * 8 + (size_t)N_VAT * 4 +
                      (size_t)N_WY * 2;  // 19519488
  const bool usefrag = (d_ws != nullptr) && (ws_size >= need);

  if (usefrag) {
    prep_wu_kernel<<<(TOUT * 768 * 64) / 256, 256, 0, stream>>>(W, U, WUf);
    prep_misc_kernel<<<(N_WA + N_UA + N_VAT + N_WY) / 256, 256, 0, stream>>>(
        Wa, Ua, Va, Wy, Waf, Uaf, Vat, Wyb);
    hipFuncSetAttribute((const void*)lstm_attn_mfma,
                        hipFuncAttributeMaxDynamicSharedMemorySize, SMEM_BYTES);
    lstm_attn_mfma<<<NB / 2, 1024, SMEM_BYTES, stream>>>(H, y0, emb, ba, bias, fcw, fcb, WUf,
                                                         Waf, Uaf, Vat, Wyb, out);
  } else {
    hipFuncSetAttribute((const void*)lstm_attn_fb,
                        hipFuncAttributeMaxDynamicSharedMemorySize, FB_SMEM_BYTES);
    lstm_attn_fb<<<NB / 2, 1024, FB_SMEM_BYTES, stream>>>(H, y0, emb, Wa, Ua, ba, Va, W, U, bias,
                                                          Wy, fcw, fcb, out);
  }
}